// Round 11
// baseline (38.563 us; speedup 1.0000x reference)
//
#include <hip/hip_runtime.h>
#include <hip/hip_bf16.h>

#define BN_EPS 1e-5f

typedef float f32x4 __attribute__((ext_vector_type(4)));
typedef __bf16 bfx8 __attribute__((ext_vector_type(8)));
typedef __bf16 bfx4 __attribute__((ext_vector_type(4)));

// Dims: batch=1024, P=64, B=16, H=64, E=64, D1=512, D2=1024.
// Dead code: softmax over singleton -> aw==1 -> attention MLP + vel emb unused;
// output rows i-independent per group -> compute once per group, broadcast.
// Rank-1 split: x = [0.05*h | at*S+wa_b]; bottom-64 rows of W1 fold to
//   at[m]*us[c] + vs[c]; p1 = relu(acc_h*s1 + at*us + vs);
// p2 = relu(p1@W2*s2+h2); out = group max, broadcast to 64 rows.

// ---------------------------------------------------------------------------
// k0 (256 thr): blocks 0..127  : w2t[1024][512] = (bf16) W2^T
//               blocks 128..135: w1t[512][64]   = (bf16) W1top^T
//               blocks 136..151: xg[1024][64]   = (bf16) 0.05*h
//               blocks 152..159: us/vs/s1 per 64-col chunk
//               block  160     : s2[1024], h2[1024]
// scsh layout (f32): [0)=s1[512] [512)=us[512] [1024)=vs[512]
//                    [1536)=s2[1024] [2560)=h2[1024]
// ---------------------------------------------------------------------------
__global__ __launch_bounds__(256) void k0_prep(
    const float* __restrict__ w2, const float* __restrict__ w1,
    const float* __restrict__ h, const float* __restrict__ at,
    const float* __restrict__ wa_w, const float* __restrict__ wa_b,
    const float* __restrict__ b1, const float* __restrict__ bn1,
    const float* __restrict__ b2, const float* __restrict__ bn2,
    __bf16* __restrict__ w2t, __bf16* __restrict__ w1t,
    __bf16* __restrict__ xg, float* __restrict__ scsh)
{
    const int t  = threadIdx.x;
    const int bx = blockIdx.x;

    if (bx < 136) {                       // transposes
        __shared__ float tile[64][69];
        int kt0, n0, src_ld, dst_ld;
        const float* src;
        __bf16* dst;
        if (bx < 128) {
            kt0 = (bx & 7) * 64;  n0 = (bx >> 3) * 64;
            src = w2; src_ld = 1024; dst = w2t; dst_ld = 512;
        } else {
            kt0 = 0;  n0 = (bx - 128) * 64;
            src = w1; src_ld = 512; dst = w1t; dst_ld = 64;
        }
        #pragma unroll
        for (int i = 0; i < 4; ++i) {
            const int idx = t + i * 256;
            const int kk  = idx >> 4;
            const int nq  = (idx & 15) * 4;
            const f32x4 val = *(const f32x4*)&src[(size_t)(kt0 + kk) * src_ld + n0 + nq];
            #pragma unroll
            for (int j = 0; j < 4; ++j) tile[kk][nq + j] = val[j];
        }
        __syncthreads();
        #pragma unroll
        for (int i = 0; i < 2; ++i) {
            const int idx = t + i * 256;
            const int n   = idx >> 3;
            const int kq  = (idx & 7) * 8;
            bfx8 o;
            #pragma unroll
            for (int j = 0; j < 8; ++j) o[j] = (__bf16)tile[kq + j][n];
            *(bfx8*)&dst[(size_t)(n0 + n) * dst_ld + kt0 + kq] = o;
        }
    } else if (bx < 152) {                // xg = 0.05*h (bf16), 64 rows/block
        const int r0 = (bx - 136) * 64;
        #pragma unroll
        for (int i = 0; i < 2; ++i) {
            const int idx = t + i * 256;          // 0..511 bfx8 slots
            const int row = idx >> 3;
            const int cg  = (idx & 7) * 8;
            const f32x4 v0 = *(const f32x4*)&h[(size_t)(r0 + row) * 64 + cg];
            const f32x4 v1 = *(const f32x4*)&h[(size_t)(r0 + row) * 64 + cg + 4];
            bfx8 o;
            #pragma unroll
            for (int j = 0; j < 4; ++j) {
                o[j]     = (__bf16)(0.05f * v0[j]);
                o[4 + j] = (__bf16)(0.05f * v1[j]);
            }
            *(bfx8*)&xg[(size_t)(r0 + row) * 64 + cg] = o;
        }
    } else if (bx < 160) {                // us/vs/s1 for 64 cols
        __shared__ float Sl[64], Wbl[64];
        __shared__ float pu[4][64], pv[4][64];
        const int c0 = (bx - 152) * 64;
        if (t < 64) {
            float s = 0.f;
            #pragma unroll
            for (int q = 0; q < 6; ++q) s += wa_w[q * 64 + t];
            Sl[t]  = 0.05f * s;
            Wbl[t] = 0.05f * wa_b[t];
        }
        __syncthreads();
        const int cl   = t & 63;
        const int eseg = t >> 6;              // 0..3, 16 e each
        float su = 0.f, sv = 0.f;
        for (int e = eseg * 16; e < eseg * 16 + 16; ++e) {
            const float w = w1[(size_t)(64 + e) * 512 + c0 + cl];
            su = fmaf(Sl[e], w, su);
            sv = fmaf(Wbl[e], w, sv);
        }
        pu[eseg][cl] = su;
        pv[eseg][cl] = sv;
        __syncthreads();
        if (t < 64) {
            const int c = c0 + t;
            const float u = pu[0][t] + pu[1][t] + pu[2][t] + pu[3][t];
            const float v = pv[0][t] + pv[1][t] + pv[2][t] + pv[3][t];
            const float s = rsqrtf(bn1[1536 + c] + BN_EPS) * bn1[c];
            const float base = (b1[c] - bn1[1024 + c]) * s + bn1[512 + c];
            scsh[c]        = s;
            scsh[512 + c]  = u * s;
            scsh[1024 + c] = v * s + base;
        }
    } else {                              // s2/h2
        #pragma unroll
        for (int i = 0; i < 4; ++i) {
            const int c = t + i * 256;
            const float s  = rsqrtf(bn2[3072 + c] + BN_EPS) * bn2[c];
            scsh[1536 + c] = s;
            scsh[2560 + c] = (b2[c] - bn2[2048 + c]) * s + bn2[1024 + c];
        }
    }
}

// ---------------------------------------------------------------------------
// kmain v3: online-K fusion, 2 blocks/CU.
// Grid (cc 32) x (b 16) = 512 blocks, 512 thr = 8 waves, ~28 KB LDS.
// Per block: out tile [64 m][32 n].  K-loop over 8 chunks of 64:
//   GEMM1 computes p1 chunk (dbuf LDS tile) while GEMM2 consumes previous
//   chunk against W2T fragments prefetched global->reg one chunk ahead.
// ---------------------------------------------------------------------------
__global__ __launch_bounds__(512, 4) void kmain(
    const __bf16* __restrict__ xg,   // [1024][64]
    const __bf16* __restrict__ w1t,  // [512][64]
    const __bf16* __restrict__ w2t,  // [1024][512]
    const float* __restrict__ at,    // [1024]
    const float* __restrict__ scsh,  // s1,us,vs,s2,h2
    float* __restrict__ out)         // [1024,1024]
{
    const int cc   = blockIdx.x;     // 32-col chunk
    const int b    = blockIdx.y;
    const int t    = threadIdx.x;
    const int wid  = t >> 6;
    const int lane = t & 63;
    const int l15  = lane & 15;
    const int lhi  = lane >> 4;

    // roles (same split works for both GEMMs)
    const int mw = wid >> 1;         // 0..3 : m-quarter (16 rows)
    const int cw = wid & 1;          // GEMM1: c-half of chunk (32 cols)
    const int nw = wid & 1;          // GEMM2: n-half (16 cols)

    __shared__ __bf16 x_lds[64][72];       // [m][k]
    __shared__ __bf16 p1c[2][64][72];      // [m][c-chunk], double-buffered
    __shared__ float  red[4][32];

    // --- preloop: stage x tile; loop-invariant params
    {
        const int row = t >> 3;
        const int cg  = (t & 7) * 8;
        *(bfx8*)&x_lds[row][cg] = *(const bfx8*)&xg[(size_t)(b * 64 + row) * 64 + cg];
    }
    const float at1 = at[b * 64 + mw * 16 + l15];
    const int   ng  = cc * 32 + nw * 16 + l15;
    const float s2  = scsh[1536 + ng];
    const float h2  = scsh[2560 + ng];

    bfx8 b1r[2][4];                  // [chunk parity][ks*2+cf]
    bfx8 b2f[2][2];                  // [chunk parity][ks]
    f32x4 sc[2], us[2], vs[2];       // params for the chunk being produced

    #define LOAD_B1R(ck, par)                                                 \
        _Pragma("unroll")                                                     \
        for (int ks = 0; ks < 2; ++ks)                                        \
            _Pragma("unroll")                                                 \
            for (int cf = 0; cf < 2; ++cf)                                    \
                b1r[par][ks * 2 + cf] = *(const bfx8*)&w1t[                   \
                    (size_t)((ck) * 64 + cw * 32 + cf * 16 + l15) * 64 +      \
                    ks * 32 + lhi * 8];

    #define LOAD_B2(ck, par)                                                  \
        _Pragma("unroll")                                                     \
        for (int ks = 0; ks < 2; ++ks)                                        \
            b2f[par][ks] = *(const bfx8*)&w2t[                                \
                (size_t)(cc * 32 + nw * 16 + l15) * 512 + (ck) * 64 +         \
                ks * 32 + lhi * 8];

    #define LOAD_PRM(ck)                                                      \
        _Pragma("unroll")                                                     \
        for (int cf = 0; cf < 2; ++cf) {                                      \
            const int c4 = (ck) * 64 + cw * 32 + cf * 16 + lhi * 4;           \
            sc[cf] = *(const f32x4*)&scsh[c4];                                \
            us[cf] = *(const f32x4*)&scsh[512 + c4];                          \
            vs[cf] = *(const f32x4*)&scsh[1024 + c4];                         \
        }

    #define GEMM1(ck, par, buf)                                               \
        {                                                                     \
            bfx8 xf[2];                                                       \
            _Pragma("unroll")                                                 \
            for (int ks = 0; ks < 2; ++ks)                                    \
                xf[ks] = *(const bfx8*)&x_lds[mw * 16 + l15][ks * 32 + lhi * 8]; \
            f32x4 acc1[2] = {};                                               \
            _Pragma("unroll")                                                 \
            for (int ks = 0; ks < 2; ++ks)                                    \
                _Pragma("unroll")                                             \
                for (int cf = 0; cf < 2; ++cf)                                \
                    acc1[cf] = __builtin_amdgcn_mfma_f32_16x16x32_bf16(       \
                        b1r[par][ks * 2 + cf], xf[ks], acc1[cf], 0, 0, 0);    \
            _Pragma("unroll")                                                 \
            for (int cf = 0; cf < 2; ++cf) {                                  \
                bfx4 pk;                                                      \
                _Pragma("unroll")                                             \
                for (int r = 0; r < 4; ++r) {                                 \
                    const float base = fmaf(at1, us[cf][r], vs[cf][r]);       \
                    pk[r] = (__bf16)fmaxf(                                    \
                        fmaf(acc1[cf][r], sc[cf][r], base), 0.f);             \
                }                                                             \
                *(bfx4*)&p1c[buf][mw * 16 + l15][cw * 32 + cf * 16 + lhi * 4] = pk; \
            }                                                                 \
        }

    // prologue: b1r(0)+prm(0); bar(x); GEMM1(0)->buf0; b2f(0), b1r(1); bar.
    LOAD_B1R(0, 0)
    LOAD_PRM(0)
    LOAD_B2(0, 0)
    __syncthreads();
    GEMM1(0, 0, 0)
    LOAD_B1R(1, 1)
    __syncthreads();

    f32x4 acc2 = {};
    #pragma unroll
    for (int ck = 0; ck < 8; ++ck) {
        const int par  = ck & 1;
        const int npar = par ^ 1;
        // issue next-chunk loads first (hide under GEMM2)
        if (ck < 7) { LOAD_B2(ck + 1, npar) LOAD_PRM(ck + 1) }
        if (ck < 6) { LOAD_B1R(ck + 2, par) }
        // GEMM2 on chunk ck from p1c[par... buf index == parity of chunk]
        #pragma unroll
        for (int ks = 0; ks < 2; ++ks) {
            const bfx8 a = *(const bfx8*)&p1c[par][mw * 16 + l15][ks * 32 + lhi * 8];
            acc2 = __builtin_amdgcn_mfma_f32_16x16x32_bf16(
                a, b2f[par][ks], acc2, 0, 0, 0);
        }
        // GEMM1 produce chunk ck+1 into the other buffer
        if (ck < 7) { GEMM1(ck + 1, npar, npar) }
        __syncthreads();
    }

    // --- epilogue-2 + pool: lane covers m = mw*16+lhi*4+r, n = ng
    {
        float mm = 0.f;                  // relu >= 0
        #pragma unroll
        for (int r = 0; r < 4; ++r)
            mm = fmaxf(mm, fmaxf(fmaf(acc2[r], s2, h2), 0.f));
        mm = fmaxf(mm, __shfl_xor(mm, 16));
        mm = fmaxf(mm, __shfl_xor(mm, 32));
        if (lane < 16) red[mw][nw * 16 + lane] = mm;
    }
    __syncthreads();

    // --- final pool over 4 m-quarters + broadcast store (64 rows x 32 cols)
    {
        const int row = t >> 3;
        const int cg  = (t & 7) * 4;
        const f32x4 r0 = *(const f32x4*)&red[0][cg];
        const f32x4 r1 = *(const f32x4*)&red[1][cg];
        const f32x4 r2 = *(const f32x4*)&red[2][cg];
        const f32x4 r3 = *(const f32x4*)&red[3][cg];
        f32x4 pv;
        #pragma unroll
        for (int j = 0; j < 4; ++j)
            pv[j] = fmaxf(fmaxf(r0[j], r1[j]), fmaxf(r2[j], r3[j]));
        *(f32x4*)&out[(size_t)(b * 64 + row) * 1024 + cc * 32 + cg] = pv;
    }
}

extern "C" void kernel_launch(void* const* d_in, const int* in_sizes, int n_in,
                              void* d_out, int out_size, void* d_ws, size_t ws_size,
                              hipStream_t stream) {
    const float* h    = (const float*)d_in[0];   // h_states  [1,1024,64]
    const float* at   = (const float*)d_in[4];   // agent_type[8,1024,1] slice 0
    const float* wa_w = (const float*)d_in[9];   // [6,64]
    const float* wa_b = (const float*)d_in[10];  // [64]
    const float* w1   = (const float*)d_in[17];  // pre1_w [128,512]
    const float* b1   = (const float*)d_in[18];  // pre1_b [512]
    const float* bn1  = (const float*)d_in[19];  // pre_bn1 [4,512]
    const float* w2   = (const float*)d_in[20];  // pre2_w [512,1024]
    const float* b2   = (const float*)d_in[21];  // pre2_b [1024]
    const float* bn2  = (const float*)d_in[22];  // pre_bn2 [4,1024]

    char* ws = (char*)d_ws;
    __bf16* w2t  = (__bf16*)ws;                              // 1 MB
    __bf16* w1t  = (__bf16*)(ws + (1 << 20));                // 64 KB
    __bf16* xg   = (__bf16*)(ws + (1 << 20) + (64 << 10));   // 128 KB
    float*  scsh = (float*)(ws + (1 << 20) + (192 << 10));   // 14 KB
    float*  out  = (float*)d_out;

    k0_prep<<<161, 256, 0, stream>>>(w2, w1, h, at, wa_w, wa_b,
                                     b1, bn1, b2, bn2, w2t, w1t, xg, scsh);
    kmain<<<dim3(32, 16), 512, 0, stream>>>(xg, w1t, w2t, at, scsh, out);
}

// Round 12
// 17.552 us; speedup vs baseline: 2.1971x; 2.1971x over previous
//
#include <hip/hip_runtime.h>
#include <hip/hip_bf16.h>

#define BN_EPS 1e-5f

typedef float f32x4 __attribute__((ext_vector_type(4)));
typedef __bf16 bfx8 __attribute__((ext_vector_type(8)));
typedef __bf16 bfx4 __attribute__((ext_vector_type(4)));

// Dims: batch=1024, P=64, B=16, H=64, E=64, D1=512, D2=1024.
// Dead code: softmax over singleton -> aw==1 -> attention MLP + vel emb unused;
// output rows i-independent per group -> compute once per group, broadcast.
// Rank-1 split: x = [0.05*h | at*S+wa_b]; bottom-64 rows of W1 fold to
//   at[m]*us[c] + vs[c]  (us = 0.05*(S@W1bot)*s1, vs = 0.05*(wa_b@W1bot)*s1+base1)
// p1 = relu(acc_h*s1 + at*us + vs); p2 = relu(p1@W2*s2+h2); out = group max.

// ---------------------------------------------------------------------------
// k0 (256 thr): blocks 0..127  : w2t[1024][512] = (bf16) W2^T
//               blocks 128..135: w1t[512][64]   = (bf16) W1top^T
//               blocks 136..151: xg[1024][64]   = (bf16) 0.05*h
//               blocks 152..159: us/vs/s1 per 64-col chunk
//               block  160     : s2[1024], h2[1024]
// scsh layout (f32): [0)=s1[512] [512)=us[512] [1024)=vs[512]
//                    [1536)=s2[1024] [2560)=h2[1024]
// ---------------------------------------------------------------------------
__global__ __launch_bounds__(256) void k0_prep(
    const float* __restrict__ w2, const float* __restrict__ w1,
    const float* __restrict__ h, const float* __restrict__ at,
    const float* __restrict__ wa_w, const float* __restrict__ wa_b,
    const float* __restrict__ b1, const float* __restrict__ bn1,
    const float* __restrict__ b2, const float* __restrict__ bn2,
    __bf16* __restrict__ w2t, __bf16* __restrict__ w1t,
    __bf16* __restrict__ xg, float* __restrict__ scsh)
{
    const int t  = threadIdx.x;
    const int bx = blockIdx.x;

    if (bx < 136) {                       // transposes
        __shared__ float tile[64][69];
        int kt0, n0, src_ld, dst_ld;
        const float* src;
        __bf16* dst;
        if (bx < 128) {
            kt0 = (bx & 7) * 64;  n0 = (bx >> 3) * 64;
            src = w2; src_ld = 1024; dst = w2t; dst_ld = 512;
        } else {
            kt0 = 0;  n0 = (bx - 128) * 64;
            src = w1; src_ld = 512; dst = w1t; dst_ld = 64;
        }
        #pragma unroll
        for (int i = 0; i < 4; ++i) {
            const int idx = t + i * 256;
            const int kk  = idx >> 4;
            const int nq  = (idx & 15) * 4;
            const f32x4 val = *(const f32x4*)&src[(size_t)(kt0 + kk) * src_ld + n0 + nq];
            #pragma unroll
            for (int j = 0; j < 4; ++j) tile[kk][nq + j] = val[j];
        }
        __syncthreads();
        #pragma unroll
        for (int i = 0; i < 2; ++i) {
            const int idx = t + i * 256;
            const int n   = idx >> 3;
            const int kq  = (idx & 7) * 8;
            bfx8 o;
            #pragma unroll
            for (int j = 0; j < 8; ++j) o[j] = (__bf16)tile[kq + j][n];
            *(bfx8*)&dst[(size_t)(n0 + n) * dst_ld + kt0 + kq] = o;
        }
    } else if (bx < 152) {                // xg = 0.05*h (bf16), 64 rows/block
        const int r0 = (bx - 136) * 64;
        #pragma unroll
        for (int i = 0; i < 2; ++i) {
            const int idx = t + i * 256;          // 0..511 bfx8 slots
            const int row = idx >> 3;
            const int cg  = (idx & 7) * 8;
            const f32x4 v0 = *(const f32x4*)&h[(size_t)(r0 + row) * 64 + cg];
            const f32x4 v1 = *(const f32x4*)&h[(size_t)(r0 + row) * 64 + cg + 4];
            bfx8 o;
            #pragma unroll
            for (int j = 0; j < 4; ++j) {
                o[j]     = (__bf16)(0.05f * v0[j]);
                o[4 + j] = (__bf16)(0.05f * v1[j]);
            }
            *(bfx8*)&xg[(size_t)(r0 + row) * 64 + cg] = o;
        }
    } else if (bx < 160) {                // us/vs/s1 for 64 cols
        __shared__ float Sl[64], Wbl[64];
        __shared__ float pu[4][64], pv[4][64];
        const int c0 = (bx - 152) * 64;
        if (t < 64) {
            float s = 0.f;
            #pragma unroll
            for (int q = 0; q < 6; ++q) s += wa_w[q * 64 + t];
            Sl[t]  = 0.05f * s;
            Wbl[t] = 0.05f * wa_b[t];
        }
        __syncthreads();
        const int cl   = t & 63;
        const int eseg = t >> 6;              // 0..3, 16 e each
        float su = 0.f, sv = 0.f;
        for (int e = eseg * 16; e < eseg * 16 + 16; ++e) {
            const float w = w1[(size_t)(64 + e) * 512 + c0 + cl];
            su = fmaf(Sl[e], w, su);
            sv = fmaf(Wbl[e], w, sv);
        }
        pu[eseg][cl] = su;
        pv[eseg][cl] = sv;
        __syncthreads();
        if (t < 64) {
            const int c = c0 + t;
            const float u = pu[0][t] + pu[1][t] + pu[2][t] + pu[3][t];
            const float v = pv[0][t] + pv[1][t] + pv[2][t] + pv[3][t];
            const float s = rsqrtf(bn1[1536 + c] + BN_EPS) * bn1[c];
            const float base = (b1[c] - bn1[1024 + c]) * s + bn1[512 + c];
            scsh[c]        = s;
            scsh[512 + c]  = u * s;
            scsh[1024 + c] = v * s + base;
        }
    } else {                              // s2/h2
        #pragma unroll
        for (int i = 0; i < 4; ++i) {
            const int c = t + i * 256;
            const float s  = rsqrtf(bn2[3072 + c] + BN_EPS) * bn2[c];
            scsh[1536 + c] = s;
            scsh[2560 + c] = (b2[c] - bn2[2048 + c]) * s + bn2[1024 + c];
        }
    }
}

// ---------------------------------------------------------------------------
// kmain (512 thr = 8 waves, ~141 KB LDS, 1 block/CU): per block (cc, b):
// GEMM1 swapped K=64 -> epilogue-1 (+rank-1 at term) -> p1 in LDS
// -> GEMM2 -> max-pool -> broadcast store.  (R5 schedule + R9 K-halving;
// best measured config of the session, 17.63 us.)
// ---------------------------------------------------------------------------
__global__ __launch_bounds__(512, 2) void kmain(
    const __bf16* __restrict__ xg,   // [1024][64]
    const __bf16* __restrict__ w1t,  // [512][64]
    const __bf16* __restrict__ w2t,  // [1024][512]
    const float* __restrict__ at,    // [1024]
    const float* __restrict__ scsh,  // s1,us,vs,s2,h2
    float* __restrict__ out)         // [1024,1024]
{
    const int cc   = blockIdx.x;
    const int b    = blockIdx.y;
    const int t    = threadIdx.x;
    const int wid  = t >> 6;
    const int lane = t & 63;
    const int l15  = lane & 15;
    const int lhi  = lane >> 4;
    const int c0w  = wid * 64;

    __shared__ __bf16 x_lds[64][72];     // [m][k], pitch 144 B (2-way banks)
    __shared__ __bf16 p1_lds[64][520];   // [m][c]
    __shared__ __bf16 B2_lds[64][520];   // [n][k]
    __shared__ float  red[4][64];

    // --- Phase 0: issue x (1 bfx8/thread), then b1r; write x; barrier.
    bfx8 xfrag;
    {
        const int row = t >> 3;
        const int cg  = (t & 7) * 8;
        xfrag = *(const bfx8*)&xg[(size_t)(b * 64 + row) * 64 + cg];
    }
    bfx8 b1r[8];
    #pragma unroll
    for (int ks = 0; ks < 2; ++ks)
        #pragma unroll
        for (int cf = 0; cf < 4; ++cf)
            b1r[ks * 4 + cf] = *(const bfx8*)&w1t[
                (size_t)(c0w + cf * 16 + l15) * 64 + ks * 32 + lhi * 8];
    {
        const int row = t >> 3;
        const int cg  = (t & 7) * 8;
        *(bfx8*)&x_lds[row][cg] = xfrag;
    }
    __syncthreads();

    // --- Phase 1: issue B2 panel + epilogue-1 params (hide under GEMM1)
    f32x4 b2stage[8];
    {
        const __bf16* base = w2t + (size_t)(cc * 64) * 512;
        #pragma unroll
        for (int i = 0; i < 8; ++i) {
            const int n = i * 8 + wid;
            b2stage[i] = *(const f32x4*)(base + (size_t)n * 512 + lane * 8);
        }
    }
    float at4[4];
    #pragma unroll
    for (int mf = 0; mf < 4; ++mf) at4[mf] = at[b * 64 + mf * 16 + l15];
    f32x4 sc[4], us[4], vs[4];
    #pragma unroll
    for (int cf = 0; cf < 4; ++cf) {
        const int c4 = c0w + cf * 16 + lhi * 4;
        sc[cf] = *(const f32x4*)&scsh[c4];
        us[cf] = *(const f32x4*)&scsh[512 + c4];
        vs[cf] = *(const f32x4*)&scsh[1024 + c4];
    }

    // --- GEMM1 swapped: D1[c][m], K=64; wave owns c-chunk wid*64
    f32x4 acc1[4][4] = {};                   // [cf][mf]
    #pragma unroll
    for (int ks = 0; ks < 2; ++ks) {
        bfx8 bf_[4];
        #pragma unroll
        for (int mf = 0; mf < 4; ++mf)
            bf_[mf] = *(const bfx8*)&x_lds[mf * 16 + l15][ks * 32 + lhi * 8];
        #pragma unroll
        for (int cf = 0; cf < 4; ++cf)
            #pragma unroll
            for (int mf = 0; mf < 4; ++mf)
                acc1[cf][mf] = __builtin_amdgcn_mfma_f32_16x16x32_bf16(
                    b1r[ks * 4 + cf], bf_[mf], acc1[cf][mf], 0, 0, 0);
    }

    // --- land B2 panel (ds pipe), then epilogue-1 (VALU overlaps)
    #pragma unroll
    for (int i = 0; i < 8; ++i) {
        const int n = i * 8 + wid;
        *(f32x4*)((char*)&B2_lds[0][0] + (size_t)n * 1040 + lane * 16) =
            b2stage[i];
    }
    #pragma unroll
    for (int cf = 0; cf < 4; ++cf)
        #pragma unroll
        for (int mf = 0; mf < 4; ++mf) {
            bfx4 pk;
            #pragma unroll
            for (int r = 0; r < 4; ++r) {
                const float base = fmaf(at4[mf], us[cf][r], vs[cf][r]);
                pk[r] = (__bf16)fmaxf(
                    fmaf(acc1[cf][mf][r], sc[cf][r], base), 0.f);
            }
            *(bfx4*)&p1_lds[mf * 16 + l15][c0w + cf * 16 + lhi * 4] = pk;
        }
    __syncthreads();

    // --- GEMM2: D2[m][n]; wave: mrow = (wid>>1)*16, n-half = wid&1
    const int mrow  = (wid >> 1) * 16;
    const int nbase = (wid & 1) * 32;
    float s2[2], h2[2];
    #pragma unroll
    for (int nf = 0; nf < 2; ++nf) {
        const int ng = cc * 64 + nbase + nf * 16 + l15;
        s2[nf] = scsh[1536 + ng];
        h2[nf] = scsh[2560 + ng];
    }
    f32x4 acc2[2] = {};
    #pragma unroll
    for (int ks = 0; ks < 16; ++ks) {
        const bfx8 a = *(const bfx8*)&p1_lds[mrow + l15][ks * 32 + lhi * 8];
        #pragma unroll
        for (int nf = 0; nf < 2; ++nf) {
            const bfx8 bb =
                *(const bfx8*)&B2_lds[nbase + nf * 16 + l15][ks * 32 + lhi * 8];
            acc2[nf] = __builtin_amdgcn_mfma_f32_16x16x32_bf16(a, bb, acc2[nf], 0, 0, 0);
        }
    }

    // --- epilogue-2 + pool over m: in-thread r, shfl over lhi
    #pragma unroll
    for (int nf = 0; nf < 2; ++nf) {
        float mm = 0.f;                      // relu >= 0
        #pragma unroll
        for (int r = 0; r < 4; ++r)
            mm = fmaxf(mm, fmaxf(fmaf(acc2[nf][r], s2[nf], h2[nf]), 0.f));
        mm = fmaxf(mm, __shfl_xor(mm, 16));
        mm = fmaxf(mm, __shfl_xor(mm, 32));
        if (lane < 16) red[wid >> 1][nbase + nf * 16 + lane] = mm;
    }
    __syncthreads();

    // --- final pool over 4 m-frags + broadcast store (vectorized)
    #pragma unroll
    for (int i = 0; i < 2; ++i) {
        const int q   = t + i * 512;
        const int row = q >> 4;
        const int cq  = (q & 15) * 4;
        const f32x4 r0 = *(const f32x4*)&red[0][cq];
        const f32x4 r1 = *(const f32x4*)&red[1][cq];
        const f32x4 r2 = *(const f32x4*)&red[2][cq];
        const f32x4 r3 = *(const f32x4*)&red[3][cq];
        f32x4 pv;
        #pragma unroll
        for (int j = 0; j < 4; ++j)
            pv[j] = fmaxf(fmaxf(r0[j], r1[j]), fmaxf(r2[j], r3[j]));
        *(f32x4*)&out[(size_t)(b * 64 + row) * 1024 + cc * 64 + cq] = pv;
    }
}

extern "C" void kernel_launch(void* const* d_in, const int* in_sizes, int n_in,
                              void* d_out, int out_size, void* d_ws, size_t ws_size,
                              hipStream_t stream) {
    const float* h    = (const float*)d_in[0];   // h_states  [1,1024,64]
    const float* at   = (const float*)d_in[4];   // agent_type[8,1024,1] slice 0
    const float* wa_w = (const float*)d_in[9];   // [6,64]
    const float* wa_b = (const float*)d_in[10];  // [64]
    const float* w1   = (const float*)d_in[17];  // pre1_w [128,512]
    const float* b1   = (const float*)d_in[18];  // pre1_b [512]
    const float* bn1  = (const float*)d_in[19];  // pre_bn1 [4,512]
    const float* w2   = (const float*)d_in[20];  // pre2_w [512,1024]
    const float* b2   = (const float*)d_in[21];  // pre2_b [1024]
    const float* bn2  = (const float*)d_in[22];  // pre_bn2 [4,1024]

    char* ws = (char*)d_ws;
    __bf16* w2t  = (__bf16*)ws;                              // 1 MB
    __bf16* w1t  = (__bf16*)(ws + (1 << 20));                // 64 KB
    __bf16* xg   = (__bf16*)(ws + (1 << 20) + (64 << 10));   // 128 KB
    float*  scsh = (float*)(ws + (1 << 20) + (192 << 10));   // 14 KB
    float*  out  = (float*)d_out;

    k0_prep<<<161, 256, 0, stream>>>(w2, w1, h, at, wa_w, wa_b,
                                     b1, bn1, b2, bn2, w2t, w1t, xg, scsh);
    kmain<<<dim3(16, 16), 512, 0, stream>>>(xg, w1t, w2t, at, scsh, out);
}